// Round 1
// baseline (1012.682 us; speedup 1.0000x reference)
//
#include <hip/hip_runtime.h>

// Problem constants (B=8, N=2048, H=2048, E=4, I=2048)
#define HDIM 2048
#define IDIM 2048
#define KD   2048
#define ME   4096   // tokens per expert (B*N/E)

// Workspace layout (requires >= 234,881,024 bytes):
//   xb    @ 0         : bf16 x regrouped [e][t][h], 4*4096*2048*2 = 64 MiB
//   w1t   @ 64 MiB    : bf16 gate_up^T  [e][d][h], 4*4096*2048*2 = 64 MiB
//   w2t   @ 128 MiB   : bf16 down^T     [e][h][i], 4*2048*2048*2 = 32 MiB
//   inter @ 160 MiB   : bf16 silu(g)*u  [e][t][i], 4*4096*2048*2 = 64 MiB

typedef __bf16 bf16x8 __attribute__((ext_vector_type(8)));
typedef float f32x4 __attribute__((ext_vector_type(4)));

__device__ __forceinline__ unsigned short f2bf(float f) {
  unsigned u = __builtin_bit_cast(unsigned, f);
  u += 0x7FFFu + ((u >> 16) & 1u);   // round-to-nearest-even
  return (unsigned short)(u >> 16);
}

__device__ __forceinline__ void gld16(const void* g, void* l) {
  __builtin_amdgcn_global_load_lds(
      (const __attribute__((address_space(1))) unsigned int*)g,
      (__attribute__((address_space(3))) unsigned int*)l, 16, 0, 0);
}

// ---- Kernel 1: convert x fp32 -> bf16, regroup rows per expert ----
// token row (b*2048 + g*4 + e)  ->  xb[e][b*512+g][h]
__global__ void __launch_bounds__(256) pack_x(const float* __restrict__ x,
                                              unsigned short* __restrict__ xb) {
  const int row = blockIdx.x;            // 0..16383 = b*2048 + n
  const int n = row & 2047;
  const int b = row >> 11;
  const int e = n & 3, g = n >> 2;
  const float4* src = (const float4*)(x + (size_t)row * HDIM);
  unsigned short* dst = xb + ((size_t)e * ME + b * 512 + g) * HDIM;
  const int t = threadIdx.x;
  float4 v0 = src[2 * t];
  float4 v1 = src[2 * t + 1];
  uint4 pk;
  pk.x = (unsigned)f2bf(v0.x) | ((unsigned)f2bf(v0.y) << 16);
  pk.y = (unsigned)f2bf(v0.z) | ((unsigned)f2bf(v0.w) << 16);
  pk.z = (unsigned)f2bf(v1.x) | ((unsigned)f2bf(v1.y) << 16);
  pk.w = (unsigned)f2bf(v1.z) | ((unsigned)f2bf(v1.w) << 16);
  *(uint4*)(dst + 8 * t) = pk;
}

// ---- Kernel 2: transpose + cast fp32 (R x C) -> bf16 (C x R), per expert z ----
__global__ void __launch_bounds__(256) transpose_cvt(const float* __restrict__ src,
                                                     unsigned short* __restrict__ dst,
                                                     int R, int C) {
  __shared__ unsigned short tile[32][33];
  const size_t eo = (size_t)blockIdx.z * R * C;
  src += eo;
  dst += eo;
  const int c0 = blockIdx.x * 32, r0 = blockIdx.y * 32;
  const int tx = threadIdx.x & 31, ty = threadIdx.x >> 5;  // ty in 0..7
#pragma unroll
  for (int j = 0; j < 4; ++j) {
    int r = r0 + ty + j * 8;
    tile[ty + j * 8][tx] = f2bf(src[(size_t)r * C + c0 + tx]);
  }
  __syncthreads();
#pragma unroll
  for (int j = 0; j < 4; ++j) {
    int c = c0 + ty + j * 8;
    dst[(size_t)c * R + r0 + tx] = tile[tx][ty + j * 8];
  }
}

// ---- Kernel 3: GEMM1 + fused SiLU-gate ----
// Block tile: 128 token rows x (64 gate cols + 64 up cols), BK=32.
// Waves 0,1 = gate rows [0,64)/[64,128); waves 2,3 = up same rows.
// Epilogue: up waves dump acc to LDS, gate waves compute silu(g)*u -> bf16 inter.
__global__ void __launch_bounds__(256) gemm1_silu(const unsigned short* __restrict__ xb,
                                                  const unsigned short* __restrict__ w1t,
                                                  unsigned short* __restrict__ inter) {
  __shared__ unsigned short SM[8192];  // As[128*32] | Bg[64*32] | Bu[64*32] (16 KiB)
  __shared__ float U[128 * 65];        // up accumulator staging (padded)
  const int e = blockIdx.z;
  const int m0 = blockIdx.x * 128;
  const int c0 = blockIdx.y * 64;      // i-tile in [0,2048)
  const int t = threadIdx.x;
  const int lane = t & 63;
  const int wave = t >> 6;
  const int wm = wave & 1;             // row half
  const int hs = wave >> 1;            // 0 = gate, 1 = up

  const unsigned short* xe = xb + (size_t)e * ME * KD;
  const unsigned short* we = w1t + (size_t)e * 4096 * KD;

  // staging: thread t -> row t/4, k-chunk (t%4)*8 (16 B per lane, LDS = base + t*16)
  const int srow = t >> 2;
  const int scol = (t & 3) * 8;
  const unsigned short* ap0 = xe + (size_t)(m0 + srow) * KD + scol;
  const unsigned short* ap1 = ap0 + (size_t)64 * KD;
  const unsigned short* bgp = we + (size_t)(c0 + srow) * KD + scol;        // gate cols
  const unsigned short* bup = bgp + (size_t)2048 * KD;                     // up cols (+2048)
  unsigned short* al0 = SM + t * 8;
  unsigned short* al1 = SM + 2048 + t * 8;
  unsigned short* bl0 = SM + 4096 + t * 8;
  unsigned short* bl1 = SM + 6144 + t * 8;
  const unsigned short* bbase = SM + 4096 + hs * 2048;

  const int qk = (lane >> 4) * 8;
  const int l15 = lane & 15;
  int a_off[4], b_off[4];
#pragma unroll
  for (int i = 0; i < 4; ++i) a_off[i] = (wm * 64 + i * 16 + l15) * 32 + qk;
#pragma unroll
  for (int j = 0; j < 4; ++j) b_off[j] = (j * 16 + l15) * 32 + qk;

  f32x4 acc[4][4] = {};

  for (int kt = 0; kt < KD / 32; ++kt) {
    __syncthreads();
    gld16(ap0, al0);
    gld16(ap1, al1);
    gld16(bgp, bl0);
    gld16(bup, bl1);
    ap0 += 32; ap1 += 32; bgp += 32; bup += 32;
    __syncthreads();
    bf16x8 a[4], b[4];
#pragma unroll
    for (int i = 0; i < 4; ++i) a[i] = *(const bf16x8*)(SM + a_off[i]);
#pragma unroll
    for (int j = 0; j < 4; ++j) b[j] = *(const bf16x8*)(bbase + b_off[j]);
#pragma unroll
    for (int i = 0; i < 4; ++i)
#pragma unroll
      for (int j = 0; j < 4; ++j)
        acc[i][j] = __builtin_amdgcn_mfma_f32_16x16x32_bf16(a[i], b[j], acc[i][j], 0, 0, 0);
  }

  // Epilogue. C/D layout: col = lane&15, row = (lane>>4)*4 + reg.
  const int quad = lane >> 4;
  if (hs == 1) {
#pragma unroll
    for (int i = 0; i < 4; ++i)
#pragma unroll
      for (int j = 0; j < 4; ++j)
#pragma unroll
        for (int r = 0; r < 4; ++r)
          U[(wm * 64 + i * 16 + quad * 4 + r) * 65 + j * 16 + l15] = acc[i][j][r];
  }
  __syncthreads();
  if (hs == 0) {
#pragma unroll
    for (int i = 0; i < 4; ++i)
#pragma unroll
      for (int j = 0; j < 4; ++j)
#pragma unroll
        for (int r = 0; r < 4; ++r) {
          int row = wm * 64 + i * 16 + quad * 4 + r;
          int col = j * 16 + l15;
          float gt = acc[i][j][r];
          float uv = U[row * 65 + col];
          float s = gt / (1.0f + __expf(-gt));   // silu(g)
          SM[row * 64 + col] = f2bf(s * uv);     // T aliases staging region (done with it)
        }
  }
  __syncthreads();
  // cooperative vectorized store of the 128x64 bf16 tile
  unsigned short* ip = inter + ((size_t)e * ME + m0) * IDIM + c0;
#pragma unroll
  for (int p = 0; p < 4; ++p) {
    int idx = p * 256 + t;
    int row = idx >> 3, part = idx & 7;
    *(uint4*)(ip + (size_t)row * IDIM + part * 8) = *(const uint4*)(SM + row * 64 + part * 8);
  }
}

// ---- Kernel 4: GEMM2, scattered fp32 output rows ----
__global__ void __launch_bounds__(256) gemm2(const unsigned short* __restrict__ inter,
                                             const unsigned short* __restrict__ w2t,
                                             float* __restrict__ out) {
  __shared__ unsigned short SM[8192];  // As[128*32] | Bs[128*32]
  const int e = blockIdx.z;
  const int m0 = blockIdx.x * 128;
  const int n0 = blockIdx.y * 128;
  const int t = threadIdx.x;
  const int lane = t & 63;
  const int wave = t >> 6;
  const int wm = wave >> 1, wn = wave & 1;

  const unsigned short* ae = inter + (size_t)e * ME * IDIM;
  const unsigned short* be = w2t + (size_t)e * HDIM * IDIM;
  const int srow = t >> 2;
  const int scol = (t & 3) * 8;
  const unsigned short* ap0 = ae + (size_t)(m0 + srow) * IDIM + scol;
  const unsigned short* ap1 = ap0 + (size_t)64 * IDIM;
  const unsigned short* bp0 = be + (size_t)(n0 + srow) * IDIM + scol;
  const unsigned short* bp1 = bp0 + (size_t)64 * IDIM;
  unsigned short* al0 = SM + t * 8;
  unsigned short* al1 = SM + 2048 + t * 8;
  unsigned short* bl0 = SM + 4096 + t * 8;
  unsigned short* bl1 = SM + 6144 + t * 8;

  const int qk = (lane >> 4) * 8;
  const int l15 = lane & 15;
  int a_off[4], b_off[4];
#pragma unroll
  for (int i = 0; i < 4; ++i) a_off[i] = (wm * 64 + i * 16 + l15) * 32 + qk;
#pragma unroll
  for (int j = 0; j < 4; ++j) b_off[j] = 4096 + (wn * 64 + j * 16 + l15) * 32 + qk;

  f32x4 acc[4][4] = {};

  for (int kt = 0; kt < IDIM / 32; ++kt) {
    __syncthreads();
    gld16(ap0, al0);
    gld16(ap1, al1);
    gld16(bp0, bl0);
    gld16(bp1, bl1);
    ap0 += 32; ap1 += 32; bp0 += 32; bp1 += 32;
    __syncthreads();
    bf16x8 a[4], b[4];
#pragma unroll
    for (int i = 0; i < 4; ++i) a[i] = *(const bf16x8*)(SM + a_off[i]);
#pragma unroll
    for (int j = 0; j < 4; ++j) b[j] = *(const bf16x8*)(SM + b_off[j]);
#pragma unroll
    for (int i = 0; i < 4; ++i)
#pragma unroll
      for (int j = 0; j < 4; ++j)
        acc[i][j] = __builtin_amdgcn_mfma_f32_16x16x32_bf16(a[i], b[j], acc[i][j], 0, 0, 0);
  }

  // scatter rows: token t -> out row b*2048 + g*4 + e  (b = t/512, g = t%512)
  const int quad = lane >> 4;
#pragma unroll
  for (int i = 0; i < 4; ++i)
#pragma unroll
    for (int r = 0; r < 4; ++r) {
      int trow = m0 + wm * 64 + i * 16 + quad * 4 + r;
      int b_ = trow >> 9, g_ = trow & 511;
      float* orow = out + ((size_t)((b_ << 11) + (g_ << 2) + e)) * HDIM + n0 + wn * 64;
#pragma unroll
      for (int j = 0; j < 4; ++j) orow[j * 16 + l15] = acc[i][j][r];
    }
}

extern "C" void kernel_launch(void* const* d_in, const int* in_sizes, int n_in,
                              void* d_out, int out_size, void* d_ws, size_t ws_size,
                              hipStream_t stream) {
  (void)in_sizes; (void)n_in; (void)out_size; (void)ws_size;
  const float* x  = (const float*)d_in[0];
  const float* w1 = (const float*)d_in[1];
  const float* w2 = (const float*)d_in[2];
  float* out = (float*)d_out;

  char* ws = (char*)d_ws;
  unsigned short* xb    = (unsigned short*)(ws);
  unsigned short* w1t   = (unsigned short*)(ws + 67108864);
  unsigned short* w2t   = (unsigned short*)(ws + 134217728);
  unsigned short* inter = (unsigned short*)(ws + 167772160);

  pack_x<<<16384, 256, 0, stream>>>(x, xb);
  transpose_cvt<<<dim3(128, 64, 4), 256, 0, stream>>>(w1, w1t, 2048, 4096);
  transpose_cvt<<<dim3(64, 64, 4), 256, 0, stream>>>(w2, w2t, 2048, 2048);
  gemm1_silu<<<dim3(32, 32, 4), 256, 0, stream>>>(xb, w1t, inter);
  gemm2<<<dim3(32, 16, 4), 256, 0, stream>>>(inter, w2t, out);
}

// Round 2
// 905.713 us; speedup vs baseline: 1.1181x; 1.1181x over previous
//
#include <hip/hip_runtime.h>

// Problem constants (B=8, N=2048, H=2048, E=4, I=2048)
#define HDIM 2048
#define IDIM 2048
#define KD   2048
#define ME   4096   // tokens per expert (B*N/E)

// Workspace layout (requires >= 234,881,024 bytes):
//   xb    @ 0         : bf16 x regrouped [e][t][h], 64 MiB
//   w1t   @ 64 MiB    : bf16 gate_up^T  [e][d][h], 64 MiB
//   w2t   @ 128 MiB   : bf16 down^T     [e][h][i], 32 MiB
//   inter @ 160 MiB   : bf16 silu(g)*u  [e][t][i], 64 MiB

typedef __bf16 bf16x8 __attribute__((ext_vector_type(8)));
typedef float f32x4 __attribute__((ext_vector_type(4)));

__device__ __forceinline__ unsigned short f2bf(float f) {
  unsigned u = __builtin_bit_cast(unsigned, f);
  u += 0x7FFFu + ((u >> 16) & 1u);   // round-to-nearest-even
  return (unsigned short)(u >> 16);
}

__device__ __forceinline__ void gld16(const void* g, void* l) {
  __builtin_amdgcn_global_load_lds(
      (const __attribute__((address_space(1))) unsigned int*)g,
      (__attribute__((address_space(3))) unsigned int*)l, 16, 0, 0);
}

// ---- Kernel 1: convert x fp32 -> bf16, regroup rows per expert ----
__global__ void __launch_bounds__(256) pack_x(const float* __restrict__ x,
                                              unsigned short* __restrict__ xb) {
  const int row = blockIdx.x;            // 0..16383 = b*2048 + n
  const int n = row & 2047;
  const int b = row >> 11;
  const int e = n & 3, g = n >> 2;
  const float4* src = (const float4*)(x + (size_t)row * HDIM);
  unsigned short* dst = xb + ((size_t)e * ME + b * 512 + g) * HDIM;
  const int t = threadIdx.x;
  float4 v0 = src[2 * t];
  float4 v1 = src[2 * t + 1];
  uint4 pk;
  pk.x = (unsigned)f2bf(v0.x) | ((unsigned)f2bf(v0.y) << 16);
  pk.y = (unsigned)f2bf(v0.z) | ((unsigned)f2bf(v0.w) << 16);
  pk.z = (unsigned)f2bf(v1.x) | ((unsigned)f2bf(v1.y) << 16);
  pk.w = (unsigned)f2bf(v1.z) | ((unsigned)f2bf(v1.w) << 16);
  *(uint4*)(dst + 8 * t) = pk;
}

// ---- Kernel 2: transpose + cast fp32 (R x C) -> bf16 (C x R), per expert z ----
__global__ void __launch_bounds__(256) transpose_cvt(const float* __restrict__ src,
                                                     unsigned short* __restrict__ dst,
                                                     int R, int C) {
  __shared__ unsigned short tile[32][33];
  const size_t eo = (size_t)blockIdx.z * R * C;
  src += eo;
  dst += eo;
  const int c0 = blockIdx.x * 32, r0 = blockIdx.y * 32;
  const int tx = threadIdx.x & 31, ty = threadIdx.x >> 5;
#pragma unroll
  for (int j = 0; j < 4; ++j) {
    int r = r0 + ty + j * 8;
    tile[ty + j * 8][tx] = f2bf(src[(size_t)r * C + c0 + tx]);
  }
  __syncthreads();
#pragma unroll
  for (int j = 0; j < 4; ++j) {
    int c = c0 + ty + j * 8;
    dst[(size_t)c * R + r0 + tx] = tile[tx][ty + j * 8];
  }
}

// ---- Kernel 3: GEMM1 + fused SiLU-gate (register-local gate*up) ----
// Block tile: 128 token rows x 64 i-cols; stages Bgate[64x32] + Bup[64x32].
// Wave (wm,wn) owns rows wm*64..+64, cols wn*32..+32 of BOTH gate and up:
//   4 A-frags, 2 gate B-frags, 2 up B-frags -> 16 MFMA/K-step (m97 ratio).
// Epilogue: silu(g)*u in registers -> bf16 tile in LDS (row stride 72 to
// break quad bank aliasing to free 2-way) -> coalesced uint4 stores.
__global__ void __launch_bounds__(256) gemm1_silu(const unsigned short* __restrict__ xb,
                                                  const unsigned short* __restrict__ w1t,
                                                  unsigned short* __restrict__ inter) {
  __shared__ unsigned short SM[9216];  // 18 KiB: staging [0,8192) ; out tile aliases, stride 72
  const int e = blockIdx.z;
  const int m0 = blockIdx.x * 128;
  const int c0 = blockIdx.y * 64;      // i-tile in [0,2048)
  const int t = threadIdx.x;
  const int lane = t & 63;
  const int wave = t >> 6;
  const int wm = wave & 1;             // row half
  const int wn = wave >> 1;            // col quarter (32 i-cols)

  const unsigned short* xe = xb + (size_t)e * ME * KD;
  const unsigned short* we = w1t + (size_t)e * 4096 * KD;

  // staging: thread t -> row t/4, k-chunk (t%4)*8 (16 B/lane, LDS = base + t*16)
  const int srow = t >> 2;
  const int scol = (t & 3) * 8;
  const unsigned short* ap0 = xe + (size_t)(m0 + srow) * KD + scol;
  const unsigned short* ap1 = ap0 + (size_t)64 * KD;
  const unsigned short* bgp = we + (size_t)(c0 + srow) * KD + scol;   // gate cols c0..c0+63
  const unsigned short* bup = bgp + (size_t)2048 * KD;                // up cols (+2048)
  unsigned short* al0 = SM + t * 8;
  unsigned short* al1 = SM + 2048 + t * 8;
  unsigned short* bl0 = SM + 4096 + t * 8;
  unsigned short* bl1 = SM + 6144 + t * 8;

  const int qk = (lane >> 4) * 8;
  const int l15 = lane & 15;
  int a_off[4], bg_off[2], bu_off[2];
#pragma unroll
  for (int i = 0; i < 4; ++i) a_off[i] = (wm * 64 + i * 16 + l15) * 32 + qk;
#pragma unroll
  for (int j = 0; j < 2; ++j) {
    bg_off[j] = 4096 + (wn * 32 + j * 16 + l15) * 32 + qk;
    bu_off[j] = 6144 + (wn * 32 + j * 16 + l15) * 32 + qk;
  }

  f32x4 accg[4][2] = {};
  f32x4 accu[4][2] = {};

  for (int kt = 0; kt < KD / 32; ++kt) {
    __syncthreads();
    gld16(ap0, al0);
    gld16(ap1, al1);
    gld16(bgp, bl0);
    gld16(bup, bl1);
    ap0 += 32; ap1 += 32; bgp += 32; bup += 32;
    __syncthreads();
    bf16x8 a[4], bg[2], bu[2];
#pragma unroll
    for (int i = 0; i < 4; ++i) a[i] = *(const bf16x8*)(SM + a_off[i]);
#pragma unroll
    for (int j = 0; j < 2; ++j) {
      bg[j] = *(const bf16x8*)(SM + bg_off[j]);
      bu[j] = *(const bf16x8*)(SM + bu_off[j]);
    }
#pragma unroll
    for (int i = 0; i < 4; ++i)
#pragma unroll
      for (int j = 0; j < 2; ++j) {
        accg[i][j] = __builtin_amdgcn_mfma_f32_16x16x32_bf16(a[i], bg[j], accg[i][j], 0, 0, 0);
        accu[i][j] = __builtin_amdgcn_mfma_f32_16x16x32_bf16(a[i], bu[j], accu[i][j], 0, 0, 0);
      }
  }

  // Epilogue: silu in registers, bf16 tile via LDS (stride 72), coalesced store.
  __syncthreads();  // staging region reused below
  const int quad = lane >> 4;
#pragma unroll
  for (int i = 0; i < 4; ++i)
#pragma unroll
    for (int j = 0; j < 2; ++j)
#pragma unroll
      for (int r = 0; r < 4; ++r) {
        int row = wm * 64 + i * 16 + quad * 4 + r;
        int col = wn * 32 + j * 16 + l15;
        float g = accg[i][j][r];
        float u = accu[i][j][r];
        float s = g / (1.0f + __expf(-g));
        SM[row * 72 + col] = f2bf(s * u);
      }
  __syncthreads();
  unsigned short* ip = inter + ((size_t)e * ME + m0) * IDIM + c0;
#pragma unroll
  for (int p = 0; p < 4; ++p) {
    int idx = p * 256 + t;
    int row = idx >> 3, part = idx & 7;
    *(uint4*)(ip + (size_t)row * IDIM + part * 8) = *(const uint4*)(SM + row * 72 + part * 8);
  }
}

// ---- Kernel 4: GEMM2, scattered fp32 output rows ----
__global__ void __launch_bounds__(256) gemm2(const unsigned short* __restrict__ inter,
                                             const unsigned short* __restrict__ w2t,
                                             float* __restrict__ out) {
  __shared__ unsigned short SM[8192];  // As[128*32] | Bs[128*32]
  const int e = blockIdx.z;
  const int m0 = blockIdx.x * 128;
  const int n0 = blockIdx.y * 128;
  const int t = threadIdx.x;
  const int lane = t & 63;
  const int wave = t >> 6;
  const int wm = wave >> 1, wn = wave & 1;

  const unsigned short* ae = inter + (size_t)e * ME * IDIM;
  const unsigned short* be = w2t + (size_t)e * HDIM * IDIM;
  const int srow = t >> 2;
  const int scol = (t & 3) * 8;
  const unsigned short* ap0 = ae + (size_t)(m0 + srow) * IDIM + scol;
  const unsigned short* ap1 = ap0 + (size_t)64 * IDIM;
  const unsigned short* bp0 = be + (size_t)(n0 + srow) * IDIM + scol;
  const unsigned short* bp1 = bp0 + (size_t)64 * IDIM;
  unsigned short* al0 = SM + t * 8;
  unsigned short* al1 = SM + 2048 + t * 8;
  unsigned short* bl0 = SM + 4096 + t * 8;
  unsigned short* bl1 = SM + 6144 + t * 8;

  const int qk = (lane >> 4) * 8;
  const int l15 = lane & 15;
  int a_off[4], b_off[4];
#pragma unroll
  for (int i = 0; i < 4; ++i) a_off[i] = (wm * 64 + i * 16 + l15) * 32 + qk;
#pragma unroll
  for (int j = 0; j < 4; ++j) b_off[j] = 4096 + (wn * 64 + j * 16 + l15) * 32 + qk;

  f32x4 acc[4][4] = {};

  for (int kt = 0; kt < IDIM / 32; ++kt) {
    __syncthreads();
    gld16(ap0, al0);
    gld16(ap1, al1);
    gld16(bp0, bl0);
    gld16(bp1, bl1);
    ap0 += 32; ap1 += 32; bp0 += 32; bp1 += 32;
    __syncthreads();
    bf16x8 a[4], b[4];
#pragma unroll
    for (int i = 0; i < 4; ++i) a[i] = *(const bf16x8*)(SM + a_off[i]);
#pragma unroll
    for (int j = 0; j < 4; ++j) b[j] = *(const bf16x8*)(SM + b_off[j]);
#pragma unroll
    for (int i = 0; i < 4; ++i)
#pragma unroll
      for (int j = 0; j < 4; ++j)
        acc[i][j] = __builtin_amdgcn_mfma_f32_16x16x32_bf16(a[i], b[j], acc[i][j], 0, 0, 0);
  }

  // scatter rows: expert-grouped row t -> out row b*2048 + g*4 + e
  const int quad = lane >> 4;
#pragma unroll
  for (int i = 0; i < 4; ++i)
#pragma unroll
    for (int r = 0; r < 4; ++r) {
      int trow = m0 + wm * 64 + i * 16 + quad * 4 + r;
      int b_ = trow >> 9, g_ = trow & 511;
      float* orow = out + ((size_t)((b_ << 11) + (g_ << 2) + e)) * HDIM + n0 + wn * 64;
#pragma unroll
      for (int j = 0; j < 4; ++j) orow[j * 16 + l15] = acc[i][j][r];
    }
}

extern "C" void kernel_launch(void* const* d_in, const int* in_sizes, int n_in,
                              void* d_out, int out_size, void* d_ws, size_t ws_size,
                              hipStream_t stream) {
  (void)in_sizes; (void)n_in; (void)out_size; (void)ws_size;
  const float* x  = (const float*)d_in[0];
  const float* w1 = (const float*)d_in[1];
  const float* w2 = (const float*)d_in[2];
  float* out = (float*)d_out;

  char* ws = (char*)d_ws;
  unsigned short* xb    = (unsigned short*)(ws);
  unsigned short* w1t   = (unsigned short*)(ws + 67108864);
  unsigned short* w2t   = (unsigned short*)(ws + 134217728);
  unsigned short* inter = (unsigned short*)(ws + 167772160);

  pack_x<<<16384, 256, 0, stream>>>(x, xb);
  transpose_cvt<<<dim3(128, 64, 4), 256, 0, stream>>>(w1, w1t, 2048, 4096);
  transpose_cvt<<<dim3(64, 64, 4), 256, 0, stream>>>(w2, w2t, 2048, 2048);
  gemm1_silu<<<dim3(32, 32, 4), 256, 0, stream>>>(xb, w1t, inter);
  gemm2<<<dim3(32, 16, 4), 256, 0, stream>>>(inter, w2t, out);
}